// Round 7
// baseline (5190.667 us; speedup 1.0000x reference)
//
#include <hip/hip_runtime.h>

namespace {
constexpr int UNITS = 2048;
constexpr int D_IN  = 96;
constexpr int BATCH = 64;
constexpr int T     = 512;
constexpr int NNZ   = 960;   // D_IN * C_IN
constexpr int C_REC = 10;

// ---- split kernel geometry: 4 blocks per batch, 512 units each ----
constexpr int QUARTERS = 4;
constexpr int QUNITS   = 512;   // units per block
constexpr int NTH      = 512;   // threads per block; 1 unit per thread

// split-kernel LDS arena (bytes)
constexpr int HOFS  = 0;        // h[2048] f32 (full state copy)      8 KB
constexpr int IAOFS = 8192;     // input_part ping (512 f32)          2 KB
constexpr int IBOFS = 10240;    // input_part pong                    2 KB
constexpr int SPLIT_LDS = IBOFS + QUNITS * 4;   // 12.5 KB

// workspace layout
constexpr int OFF16_OFS = 0;                          // u16 [4][10][512] gather offsets
constexpr int WTAB_OFS  = OFF16_OFS + 4*10*512*2;     // f32 [4][10][512] gather weights
constexpr int LROW_OFS  = WTAB_OFS  + 4*10*512*4;     // int [4][512] COO row
constexpr int LCOL_OFS  = LROW_OFS  + 4*512*4;        // int [4][512] COO local col byte-off
constexpr int LVAL_OFS  = LCOL_OFS  + 4*512*4;        // f32 [4][512] COO val
constexpr int CNT_OFS   = LVAL_OFS  + 4*512*4;        // int [4]
constexpr int FLAG_OFS  = CNT_OFS   + 16;             // uint [64] per-batch step flags
constexpr int WS_NEED   = FLAG_OFS  + 64*4;           // 147728 B (< 163840 proven available)
}

typedef float f32x2 __attribute__((ext_vector_type(2)));
typedef float f32x4 __attribute__((ext_vector_type(4)));

// lgkm-only barrier (no vmcnt drain)
__device__ __forceinline__ void bar_lds() {
  asm volatile("s_waitcnt lgkmcnt(0)\n\ts_barrier" ::: "memory");
}

__device__ __forceinline__ float fast_tanh(float x) {
  float e = __expf(2.0f * x);
  return 1.0f - __fdividef(2.0f, e + 1.0f);
}

// ---------------------------------------------------------------------------
// prep: (a) blocks 0..31 = per-(quarter,wave) greedy bank scheduling of the 10
// gather entries (order-only, single h copy) — same joint-greedy that cut
// conflicts 58% in R6, now wavefront-parallel (64-thread blocks, ~10us total
// instead of 126us serial). (b) block 32 = deterministic counting-sort
// partition of the 960 COO entries by target quarter.
// ---------------------------------------------------------------------------
__global__ __launch_bounds__(64) void prep_split(
    const int* __restrict__ ridx, const float* __restrict__ rvals,
    const int* __restrict__ krows, const int* __restrict__ kcols,
    const float* __restrict__ kvals,
    unsigned short* __restrict__ offs16, float* __restrict__ wtab,
    int* __restrict__ lrow, int* __restrict__ lcol, float* __restrict__ lval,
    int* __restrict__ cnt)
{
  const int bid = blockIdx.x, l = threadIdx.x;
  if (bid < 32) {
    const int q = bid >> 3, w = bid & 7;
    __shared__ unsigned char hist[10][32];
    if (l < 32) for (int s = 0; s < 10; ++s) hist[s][l] = 0;
    __syncthreads();
    unsigned rem = 0x3FF;
    const int u = q * QUNITS + w * 64 + l;
    for (int step = 0; step < 10 + 63; ++step) {
      const int s = step - l;          // anti-diagonal: lane l handles slot s
      if (s >= 0 && s < 10) {
        int beste = 0, bestload = 999, bestidx = 0;
        for (int e = 0; e < C_REC; ++e) {
          if (!((rem >> e) & 1)) continue;
          int idx = ridx[u * C_REC + e];
          int ld  = hist[s][idx & 31];
          if (ld < bestload) { bestload = ld; beste = e; bestidx = idx; }
        }
        hist[s][bestidx & 31] = (unsigned char)(bestload + 1);
        rem &= ~(1u << beste);
        offs16[(q * 10 + s) * NTH + w * 64 + l] = (unsigned short)(bestidx * 4);
        wtab  [(q * 10 + s) * NTH + w * 64 + l] = rvals[u * C_REC + beste];
      }
      __syncthreads();
    }
  } else {
    // deterministic two-pass counting sort (64 threads x 15 entries)
    __shared__ int lc[64][4];
    __shared__ int base[64][4];
    int c[4] = {0, 0, 0, 0};
    for (int k = 0; k < NNZ / 64; ++k) c[kcols[l * (NNZ / 64) + k] >> 9]++;
    for (int q = 0; q < 4; ++q) lc[l][q] = c[q];
    __syncthreads();
    if (l < 4) {                        // serial scan over 64 threads, per q
      int run = 0;
      for (int t = 0; t < 64; ++t) { base[t][l] = run; run += lc[t][l]; }
      cnt[l] = run;
    }
    __syncthreads();
    int pos[4];
    for (int q = 0; q < 4; ++q) pos[q] = base[l][q];
    for (int k = 0; k < NNZ / 64; ++k) {
      const int i = l * (NNZ / 64) + k;
      const int q = kcols[i] >> 9;
      const int p = pos[q]++;
      lrow[q * NTH + p] = krows[i];
      lcol[q * NTH + p] = (kcols[i] & (QUNITS - 1)) * 4;
      lval[q * NTH + p] = kvals[i];
    }
  }
}

// gather table hoist: named scalars (R3 lesson: arrays -> scratch)
#define RD(n)                                                                  \
  const int   oa##n = (int)offs16[(q * 10 + (n)) * NTH + tid];                 \
  const float va##n = wtab[(q * 10 + (n)) * NTH + tid];

// ---------------------------------------------------------------------------
// split main kernel: 256 blocks (= 64 batches x 4 quarters), 512 threads.
// d_out doubles as the h mailbox (each row written exactly once -> no reuse
// race); per-batch monotonic flag gates row visibility. Quarters of a batch
// share bid%8 -> same XCD under round-robin dispatch (perf heuristic only;
// agent-scope atomics keep it correct on any placement).
// ---------------------------------------------------------------------------
__global__ __launch_bounds__(NTH) void reservoir_split(
    const float* __restrict__ inputs, const float* __restrict__ state0,
    const float* __restrict__ bias,
    const unsigned short* __restrict__ offs16, const float* __restrict__ wtab,
    const int* __restrict__ lrow, const int* __restrict__ lcol,
    const float* __restrict__ lval, const int* __restrict__ cnt,
    unsigned int* __restrict__ flags, float* __restrict__ out)
{
  __shared__ __align__(16) char smem[SPLIT_LDS];
  const int tid = threadIdx.x;
  const int bid = blockIdx.x;
  const int x8  = bid & 7;                 // XCD slot under round-robin
  const int i   = bid >> 3;                // 0..31
  const int q   = i & 3;                   // quarter
  const int b   = (i >> 2) * 8 + x8;       // batch

  // stage h(0) from state0; zero input_part ping+pong
  *(f32x4*)(smem + HOFS + tid * 16) = *(const f32x4*)(state0 + b * UNITS + tid * 4);
  *(float*)(smem + IAOFS + tid * 4) = 0.f;
  *(float*)(smem + IBOFS + tid * 4) = 0.f;

  RD(0) RD(1) RD(2) RD(3) RD(4) RD(5) RD(6) RD(7) RD(8) RD(9)

  const float biasr = bias[q * QUNITS + tid];

  // this thread's input-COO entry for this quarter (cnt[q] ~ 240 << 512)
  const int  cq = cnt[q];
  const bool e0 = tid < cq;
  const int   r0 = e0 ? lrow[q * NTH + tid] : 0;
  const int   c0 = e0 ? lcol[q * NTH + tid] : 0;
  const float v0 = e0 ? lval[q * NTH + tid] : 0.f;

  const float* xin  = inputs + (size_t)b * (T * D_IN);
  unsigned int* flag = flags + b;
  float* outq = out + (size_t)b * T * UNITS + q * QUNITS;  // this block's slice

  float xn = e0 ? xin[r0] : 0.f;           // x(0)
  __syncthreads();
  if (e0) atomicAdd((float*)(smem + IAOFS + c0), xn * v0);   // prime input(0)
  xn = e0 ? xin[D_IN + r0] : 0.f;          // prefetch x(1)
  bar_lds();

#pragma unroll 1
  for (int t = 0; t < T; ++t) {
    const int ir = IAOFS + ((t & 1) << 11);
    const int iw = IAOFS + (((t + 1) & 1) << 11);
    // consume input_part(t), re-zero for reuse at t+2
    float s = *(float*)(smem + ir + tid * 4) + biasr;
    *(float*)(smem + ir + tid * 4) = 0.f;
    // 10 scheduled gathers from the full-state LDS copy
    s += *(const float*)(smem + HOFS + oa0) * va0;
    s += *(const float*)(smem + HOFS + oa1) * va1;
    s += *(const float*)(smem + HOFS + oa2) * va2;
    s += *(const float*)(smem + HOFS + oa3) * va3;
    s += *(const float*)(smem + HOFS + oa4) * va4;
    s += *(const float*)(smem + HOFS + oa5) * va5;
    s += *(const float*)(smem + HOFS + oa6) * va6;
    s += *(const float*)(smem + HOFS + oa7) * va7;
    s += *(const float*)(smem + HOFS + oa8) * va8;
    s += *(const float*)(smem + HOFS + oa9) * va9;
    // scatter input_part(t+1) while gathers/tanh are in flight
    if (t < T - 1 && e0) atomicAdd((float*)(smem + iw + c0), xn * v0);
    const float hn = fast_tanh(s);
    // publish h(t+1) quarter = the output row itself (agent-visible store)
    __hip_atomic_store((unsigned int*)(outq + (size_t)t * UNITS) + tid,
                       __builtin_bit_cast(unsigned int, hn),
                       __ATOMIC_RELAXED, __HIP_MEMORY_SCOPE_AGENT);
    if (t == T - 1) break;
    __syncthreads();                       // vmcnt(0): publishes are visible
    if (tid == 0) {
      __hip_atomic_fetch_add(flag, 1u, __ATOMIC_RELEASE, __HIP_MEMORY_SCOPE_AGENT);
      const unsigned tgt = 4u * (unsigned)(t + 1);
      while (__hip_atomic_load(flag, __ATOMIC_ACQUIRE, __HIP_MEMORY_SCOPE_AGENT) < tgt) {}
    }
    __syncthreads();
    // stage h(t+1): read the full just-published row from L2
    const unsigned long long* row =
        (const unsigned long long*)(out + ((size_t)b * T + t) * UNITS);
    unsigned long long p0 = __hip_atomic_load(row + tid * 2,
                                              __ATOMIC_RELAXED, __HIP_MEMORY_SCOPE_AGENT);
    unsigned long long p1 = __hip_atomic_load(row + tid * 2 + 1,
                                              __ATOMIC_RELAXED, __HIP_MEMORY_SCOPE_AGENT);
    *(f32x2*)(smem + HOFS + tid * 16)     = __builtin_bit_cast(f32x2, p0);
    *(f32x2*)(smem + HOFS + tid * 16 + 8) = __builtin_bit_cast(f32x2, p1);
    // prefetch x(t+2) (stays in flight across the lgkm-only barrier)
    if (e0) xn = xin[(t + 2 < T ? t + 2 : T - 1) * D_IN + r0];
    bar_lds();                             // staged h visible for next gather
  }
}

// ---------------------------------------------------------------------------
// fallback (ws too small; never expected to run): R6-style one block/batch,
// direct un-scheduled gathers, x read straight from global with prefetch.
// ---------------------------------------------------------------------------
#define MRD(n)                                                                 \
  const int   ja##n = ridx[u0 * C_REC + (n)] * 4;                              \
  const float ua##n = rvals[u0 * C_REC + (n)];                                 \
  const int   jb##n = ridx[(u0 + 1) * C_REC + (n)] * 4;                        \
  const float ub##n = rvals[(u0 + 1) * C_REC + (n)];

__global__ __launch_bounds__(1024) void reservoir_mono(
    const float* __restrict__ inputs, const float* __restrict__ state0,
    const float* __restrict__ kvals,  const float* __restrict__ rvals,
    const float* __restrict__ bias,   const int* __restrict__ krows,
    const int* __restrict__ kcols,    const int* __restrict__ ridx,
    float* __restrict__ out)
{
  __shared__ __align__(16) char smem[32768];  // hA 8K | hB 8K | IA 8K | IB 8K
  const int tid = threadIdx.x, b = blockIdx.x, u0 = tid * 2;
  *(f32x2*)(smem + 16384 + tid * 8) = (f32x2){0.f, 0.f};
  *(f32x2*)(smem + 24576 + tid * 8) = (f32x2){0.f, 0.f};
  *(f32x2*)(smem + tid * 8) = *(const f32x2*)(state0 + b * UNITS + u0);
  MRD(0) MRD(1) MRD(2) MRD(3) MRD(4) MRD(5) MRD(6) MRD(7) MRD(8) MRD(9)
  const f32x2 bias2 = *(const f32x2*)(bias + u0);
  const bool e0 = tid < NNZ;
  const int   r0 = e0 ? krows[tid] : 0;
  const int   c0 = e0 ? kcols[tid] * 4 : 0;
  const float v0 = e0 ? kvals[tid] : 0.f;
  const float* xin  = inputs + (size_t)b * (T * D_IN);
  f32x2*       outp = (f32x2*)out + (size_t)b * (T * (UNITS / 2)) + tid;
  float xn = e0 ? xin[r0] : 0.f;
  __syncthreads();
  if (e0) atomicAdd((float*)(smem + 16384 + c0), xn * v0);
  xn = e0 ? xin[D_IN + r0] : 0.f;
  bar_lds();
#pragma unroll 1
  for (int t = 0; t < T; ++t) {
    const int hc = (t & 1) ? 8192 : 0, hn = (t & 1) ? 0 : 8192;
    const int ir = 16384 + ((t & 1) << 13), iw = 16384 + (((t + 1) & 1) << 13);
    f32x2 in2 = *(f32x2*)(smem + ir + tid * 8);
    *(f32x2*)(smem + ir + tid * 8) = (f32x2){0.f, 0.f};
    float s0 = in2.x + bias2.x, s1 = in2.y + bias2.y;
    s0 += *(const float*)(smem + hc + ja0) * ua0; s1 += *(const float*)(smem + hc + jb0) * ub0;
    s0 += *(const float*)(smem + hc + ja1) * ua1; s1 += *(const float*)(smem + hc + jb1) * ub1;
    s0 += *(const float*)(smem + hc + ja2) * ua2; s1 += *(const float*)(smem + hc + jb2) * ub2;
    s0 += *(const float*)(smem + hc + ja3) * ua3; s1 += *(const float*)(smem + hc + jb3) * ub3;
    s0 += *(const float*)(smem + hc + ja4) * ua4; s1 += *(const float*)(smem + hc + jb4) * ub4;
    s0 += *(const float*)(smem + hc + ja5) * ua5; s1 += *(const float*)(smem + hc + jb5) * ub5;
    s0 += *(const float*)(smem + hc + ja6) * ua6; s1 += *(const float*)(smem + hc + jb6) * ub6;
    s0 += *(const float*)(smem + hc + ja7) * ua7; s1 += *(const float*)(smem + hc + jb7) * ub7;
    s0 += *(const float*)(smem + hc + ja8) * ua8; s1 += *(const float*)(smem + hc + jb8) * ub8;
    s0 += *(const float*)(smem + hc + ja9) * ua9; s1 += *(const float*)(smem + hc + jb9) * ub9;
    if (t < T - 1 && e0) atomicAdd((float*)(smem + iw + c0), xn * v0);
    f32x2 hh = {fast_tanh(s0), fast_tanh(s1)};
    *(f32x2*)(smem + hn + tid * 8) = hh;
    __builtin_nontemporal_store(hh, outp + (size_t)t * (UNITS / 2));
    if (e0) xn = xin[(t + 2 < T ? t + 2 : T - 1) * D_IN + r0];
    bar_lds();
  }
}

extern "C" void kernel_launch(void* const* d_in, const int* in_sizes, int n_in,
                              void* d_out, int out_size, void* d_ws, size_t ws_size,
                              hipStream_t stream) {
  const float* inputs = (const float*)d_in[0];
  const float* state0 = (const float*)d_in[1];
  const float* kvals  = (const float*)d_in[2];
  const float* rvals  = (const float*)d_in[3];
  const float* bias   = (const float*)d_in[4];
  const int*   krows  = (const int*)d_in[5];
  const int*   kcols  = (const int*)d_in[6];
  const int*   ridx   = (const int*)d_in[7];

  if (ws_size >= (size_t)WS_NEED) {
    unsigned short* offs16 = (unsigned short*)((char*)d_ws + OFF16_OFS);
    float* wtab = (float*)((char*)d_ws + WTAB_OFS);
    int*   lrow = (int*)((char*)d_ws + LROW_OFS);
    int*   lcol = (int*)((char*)d_ws + LCOL_OFS);
    float* lval = (float*)((char*)d_ws + LVAL_OFS);
    int*   cnt  = (int*)((char*)d_ws + CNT_OFS);
    unsigned int* flags = (unsigned int*)((char*)d_ws + FLAG_OFS);

    hipMemsetAsync(flags, 0, 64 * sizeof(unsigned int), stream);
    prep_split<<<dim3(33), dim3(64), 0, stream>>>(
        ridx, rvals, krows, kcols, kvals, offs16, wtab, lrow, lcol, lval, cnt);
    reservoir_split<<<dim3(256), dim3(NTH), 0, stream>>>(
        inputs, state0, bias, offs16, wtab, lrow, lcol, lval, cnt, flags,
        (float*)d_out);
  } else {
    reservoir_mono<<<dim3(BATCH), dim3(1024), 0, stream>>>(
        inputs, state0, kvals, rvals, bias, krows, kcols, ridx, (float*)d_out);
  }
}

// Round 8
// 1906.339 us; speedup vs baseline: 2.7228x; 2.7228x over previous
//
#include <hip/hip_runtime.h>

namespace {
constexpr int UNITS = 2048;
constexpr int D_IN  = 96;
constexpr int BATCH = 64;
constexpr int T     = 512;
constexpr int NNZ   = 960;   // D_IN * C_IN
constexpr int C_REC = 10;
constexpr int NT    = 1024;  // threads/block; thread owns units 2t,2t+1 x 2 batches

// LDS arena (bytes). Two batches interleaved: value of unit u, batch p lives
// at dword 2u+p (byte 8u+4p). One ds_read_b64 at 8*idx gathers BOTH batches.
constexpr int HA = 0;        // h ping  [2048][2] f32 = 16 KB
constexpr int HB = 16384;    // h pong
constexpr int IA = 32768;    // input_part ping, interleaved, 16 KB
constexpr int IB = 49152;    // input_part pong
constexpr int LDS_BYTES = 65536;

// workspace: scheduled gather tables [slot 0..19][tid] coalesced
constexpr int OFFS_OFS = 0;                 // int  [20][1024] byte offsets (8*idx)
constexpr int WTAB_OFS = 20 * NT * 4;       // f32  [20][1024]
constexpr int WS_NEED  = 40 * NT * 4;       // 163840 B (same as R6's, proven available)
}

typedef float f32x2 __attribute__((ext_vector_type(2)));
typedef float f32x4 __attribute__((ext_vector_type(4)));

// lgkm-only barrier: __syncthreads() drains vmcnt(0) -> would stall on the
// streaming out-stores and x prefetches every step.
__device__ __forceinline__ void bar_lds() {
  asm volatile("s_waitcnt lgkmcnt(0)\n\ts_barrier" ::: "memory");
}

__device__ __forceinline__ float fast_tanh(float x) {
  float e = __expf(2.0f * x);
  return 1.0f - __fdividef(2.0f, e + 1.0f);
}

// ---------------------------------------------------------------------------
// Parallel prep (R6's 126us serial prep was ~10% of wall): 16 blocks, one per
// main-kernel wave; 64 lanes; anti-diagonal greedy over 20 gather slots.
// b64 gathers span bank pair (2*idx, 2*idx+1) -> bin = idx & 15. Greedy
// reorder-only: per slot, lane picks its remaining entry minimizing the
// slot's bin load (sequential across lanes = R6-quality schedule).
// ---------------------------------------------------------------------------
__global__ __launch_bounds__(64) void prep_sched(
    const int* __restrict__ ridx, const float* __restrict__ rvals,
    int* __restrict__ offs, float* __restrict__ wtab)
{
  const int w = blockIdx.x, l = threadIdx.x;
  __shared__ unsigned char hist[20][16];
  if (l < 16)
    for (int s = 0; s < 20; ++s) hist[s][l] = 0;
  __syncthreads();
  const int tidm = w * 64 + l;          // main-kernel tid
  const int uA = 2 * tidm, uB = uA + 1;
  unsigned remA = 0x3FF, remB = 0x3FF;
  for (int step = 0; step < 20 + 63; ++step) {
    const int s = step - l;             // lane l handles slot s this step
    if (s >= 0 && s < 20) {
      const int u = (s & 1) ? uB : uA;
      unsigned& rem = (s & 1) ? remB : remA;
      int beste = 0, bestload = 999, bestidx = 0;
      for (int e = 0; e < C_REC; ++e) {
        if (!((rem >> e) & 1)) continue;
        int idx = ridx[u * C_REC + e];
        int ld  = hist[s][idx & 15];
        if (ld < bestload) { bestload = ld; beste = e; bestidx = idx; }
      }
      hist[s][bestidx & 15] = (unsigned char)(bestload + 1);
      rem &= ~(1u << beste);
      offs[s * NT + tidm] = bestidx * 8;
      wtab[s * NT + tidm] = rvals[u * C_REC + beste];
    }
    __syncthreads();
  }
}

// named-scalar hoist (R3 lesson: arrays -> scratch). Even slots feed unit A
// (u0), odd slots unit B (u0+1).
#define RDECL(k)                                                               \
  const int   oA##k = PERM ? offs[(2*(k)) * NT + tid]                          \
                           : ridx[u0 * C_REC + (k)] * 8;                       \
  const float wA##k = PERM ? wtab[(2*(k)) * NT + tid]                          \
                           : rvals[u0 * C_REC + (k)];                          \
  const int   oB##k = PERM ? offs[(2*(k)+1) * NT + tid]                        \
                           : ridx[(u0 + 1) * C_REC + (k)] * 8;                 \
  const float wB##k = PERM ? wtab[(2*(k)+1) * NT + tid]                        \
                           : rvals[(u0 + 1) * C_REC + (k)];

#define GAT(HC, k)                                                             \
  { f32x2 ga = *(const f32x2*)(smem + (HC) + oA##k);                           \
    s0a += ga.x * wA##k; s0b += ga.y * wA##k;                                  \
    f32x2 gb = *(const f32x2*)(smem + (HC) + oB##k);                           \
    s1a += gb.x * wB##k; s1b += gb.y * wB##k; }

// One timestep for BOTH batches. HC/HN = h cur/next, IR = input consumed
// (read+re-zero, b128 covers 2 units x 2 batches), IW = input built for t+1.
// xa/xb hold x(t+1) entering the step; prefetch x(t+2) after the scatter.
#define STEP(HC, HN, IR, IW, DO_SCATTER, TSTEP)                                \
  {                                                                            \
    f32x4 in4 = *(f32x4*)(smem + (IR) + tid * 16);                             \
    *(f32x4*)(smem + (IR) + tid * 16) = (f32x4){0.f, 0.f, 0.f, 0.f};           \
    float s0a = in4.x + bias2.x, s0b = in4.y + bias2.x;                        \
    float s1a = in4.z + bias2.y, s1b = in4.w + bias2.y;                        \
    GAT(HC, 0) GAT(HC, 1) GAT(HC, 2) GAT(HC, 3) GAT(HC, 4)                     \
    GAT(HC, 5) GAT(HC, 6) GAT(HC, 7) GAT(HC, 8) GAT(HC, 9)                     \
    if ((DO_SCATTER) && e0) {                                                  \
      atomicAdd((float*)(smem + (IW) + kcb),     xa * kv);                     \
      atomicAdd((float*)(smem + (IW) + kcb + 4), xb * kv);                     \
    }                                                                          \
    f32x4 hh = {fast_tanh(s0a), fast_tanh(s0b),                                \
                fast_tanh(s1a), fast_tanh(s1b)};                               \
    *(f32x4*)(smem + (HN) + tid * 16) = hh;                                    \
    __builtin_nontemporal_store((f32x2){hh.x, hh.z},                           \
                                out0 + (size_t)(TSTEP) * (UNITS / 2));         \
    __builtin_nontemporal_store((f32x2){hh.y, hh.w},                           \
                                out1 + (size_t)(TSTEP) * (UNITS / 2));         \
    if (e0) {                                                                  \
      int tnx = (TSTEP) + 2 < T ? (TSTEP) + 2 : T - 1;                         \
      xa = xin0[tnx * D_IN + r0];                                              \
      xb = xin1[tnx * D_IN + r0];                                              \
    }                                                                          \
    bar_lds();                                                                 \
  }

template <bool PERM>
__global__ __launch_bounds__(NT, 4) void reservoir2(
    const float* __restrict__ inputs, const float* __restrict__ state0,
    const float* __restrict__ kvals,  const float* __restrict__ rvals,
    const float* __restrict__ bias,   const int* __restrict__ krows,
    const int* __restrict__ kcols,    const int* __restrict__ ridx,
    const int* __restrict__ offs,     const float* __restrict__ wtab,
    float* __restrict__ out)
{
  __shared__ __align__(16) char smem[LDS_BYTES];
  const int tid = threadIdx.x;
  const int b0  = 2 * blockIdx.x, b1 = b0 + 1;   // this block's 2 batches
  const int u0  = 2 * tid;

  // zero input ping+pong; stage h(0) interleaved {u0b0,u0b1,u1b0,u1b1}
  *(f32x4*)(smem + IA + tid * 16) = (f32x4){0.f, 0.f, 0.f, 0.f};
  *(f32x4*)(smem + IB + tid * 16) = (f32x4){0.f, 0.f, 0.f, 0.f};
  f32x2 h0a = *(const f32x2*)(state0 + b0 * UNITS + u0);
  f32x2 h0b = *(const f32x2*)(state0 + b1 * UNITS + u0);
  *(f32x4*)(smem + HA + tid * 16) = (f32x4){h0a.x, h0b.x, h0a.y, h0b.y};

  RDECL(0) RDECL(1) RDECL(2) RDECL(3) RDECL(4)
  RDECL(5) RDECL(6) RDECL(7) RDECL(8) RDECL(9)

  const f32x2 bias2 = *(const f32x2*)(bias + u0);

  // input COO entry (interleaved col byte offset = col*8; +0 batch0, +4 batch1)
  const bool e0 = tid < NNZ;
  const int   r0  = e0 ? krows[tid] : 0;
  const int   kcb = e0 ? kcols[tid] * 8 : 0;
  const float kv  = e0 ? kvals[tid] : 0.f;

  const float* xin0 = inputs + (size_t)b0 * (T * D_IN);
  const float* xin1 = inputs + (size_t)b1 * (T * D_IN);
  f32x2* out0 = (f32x2*)out + (size_t)b0 * (T * (UNITS / 2)) + tid;
  f32x2* out1 = (f32x2*)out + (size_t)b1 * (T * (UNITS / 2)) + tid;

  float xa = e0 ? xin0[r0] : 0.f;   // x(0)
  float xb = e0 ? xin1[r0] : 0.f;
  __syncthreads();
  if (e0) {                          // prime input(0) -> IA
    atomicAdd((float*)(smem + IA + kcb),     xa * kv);
    atomicAdd((float*)(smem + IA + kcb + 4), xb * kv);
  }
  if (e0) { xa = xin0[D_IN + r0]; xb = xin1[D_IN + r0]; }   // x(1)
  bar_lds();

#pragma unroll 1
  for (int ts = 0; ts < T; ts += 2) {
    STEP(HA, HB, IA, IB, true,         ts);
    STEP(HB, HA, IB, IA, (ts + 2) < T, ts + 1);
  }
}

extern "C" void kernel_launch(void* const* d_in, const int* in_sizes, int n_in,
                              void* d_out, int out_size, void* d_ws, size_t ws_size,
                              hipStream_t stream) {
  const float* inputs = (const float*)d_in[0];
  const float* state0 = (const float*)d_in[1];
  const float* kvals  = (const float*)d_in[2];
  const float* rvals  = (const float*)d_in[3];
  const float* bias   = (const float*)d_in[4];
  const int*   krows  = (const int*)d_in[5];
  const int*   kcols  = (const int*)d_in[6];
  const int*   ridx   = (const int*)d_in[7];

  int*   offs = (int*)((char*)d_ws + OFFS_OFS);
  float* wtab = (float*)((char*)d_ws + WTAB_OFS);

  if (ws_size >= (size_t)WS_NEED) {
    prep_sched<<<dim3(16), dim3(64), 0, stream>>>(ridx, rvals, offs, wtab);
    reservoir2<true><<<dim3(BATCH / 2), dim3(NT), 0, stream>>>(
        inputs, state0, kvals, rvals, bias, krows, kcols, ridx, offs, wtab,
        (float*)d_out);
  } else {
    reservoir2<false><<<dim3(BATCH / 2), dim3(NT), 0, stream>>>(
        inputs, state0, kvals, rvals, bias, krows, kcols, ridx, offs, wtab,
        (float*)d_out);
  }
}

// Round 9
// 1253.519 us; speedup vs baseline: 4.1409x; 1.5208x over previous
//
#include <hip/hip_runtime.h>

namespace {
constexpr int UNITS = 2048;
constexpr int D_IN  = 96;
constexpr int BATCH = 64;
constexpr int T     = 512;
constexpr int NNZ   = 960;   // D_IN * C_IN
constexpr int C_REC = 10;
constexpr int NT    = 1024;  // threads/block; thread owns units 2t, 2t+1
constexpr int NCOPY = 4;     // h replication factor (bank-choice scheduling)

// LDS arena (bytes). h ping/pong each hold 4 copies; copy c is barrel-shifted
// by 8c dwords: value of unit u lives at dword ((u + 8c) & 2047) of copy c.
// A gather of unit u can read any of banks {u, u+8, u+16, u+24} & 31.
constexpr int HA = 0;        // 4 x 8 KB
constexpr int HB = 32768;    // 4 x 8 KB
constexpr int IA = 65536;    // input_part ping (8 KB)
constexpr int IB = 73728;    // input_part pong (8 KB)
constexpr int LDS_BYTES = 81920;

// workspace: scheduled gather tables, [slot 0..19][tid] coalesced
constexpr int OFFS_OFS = 0;              // int  [20][1024] final LDS byte offsets
constexpr int WTAB_OFS = 20 * NT * 4;    // f32  [20][1024]
constexpr int WS_NEED  = 40 * NT * 4;    // 163840 B (proven available in R6/R8)
}

typedef float f32x2 __attribute__((ext_vector_type(2)));
typedef float f32x4 __attribute__((ext_vector_type(4)));

// lgkm-only barrier: __syncthreads() drains vmcnt(0) -> would stall on the
// streaming out-stores and x prefetch loads every step.
__device__ __forceinline__ void bar_lds() {
  asm volatile("s_waitcnt lgkmcnt(0)\n\ts_barrier" ::: "memory");
}

__device__ __forceinline__ float fast_tanh(float x) {
  float e = __expf(2.0f * x);
  return 1.0f - __fdividef(2.0f, e + 1.0f);
}

// ---------------------------------------------------------------------------
// Parallel prep: 16 blocks (one per main-kernel wave) x 64 lanes. Stages the
// wave's 1280 (idx,w) entries in LDS first (R8's prep re-read global ridx
// inside the greedy loop -> ~100us; staged version is ~10us). Anti-diagonal
// greedy: for gather slot s, lanes 0..63 sequentially pick (remaining entry,
// copy 0..3) minimizing the slot's per-bank load. 4 choices per entry ->
// expected max-load ~2 (free per m136).
// ---------------------------------------------------------------------------
__global__ __launch_bounds__(64) void prep_sched(
    const int* __restrict__ ridx, const float* __restrict__ rvals,
    int* __restrict__ offs, float* __restrict__ wtab)
{
  const int w = blockIdx.x, l = threadIdx.x;
  __shared__ int           sidx[128 * C_REC];
  __shared__ float         sval[128 * C_REC];
  __shared__ unsigned char hist[20][32];
  for (int i = l; i < 128 * C_REC; i += 64) {
    sidx[i] = ridx[w * 128 * C_REC + i];
    sval[i] = rvals[w * 128 * C_REC + i];
  }
  if (l < 32)
    for (int s = 0; s < 20; ++s) hist[s][l] = 0;
  __syncthreads();

  unsigned remA = 0x3FF, remB = 0x3FF;
  for (int step = 0; step < 20 + 63; ++step) {
    const int s = step - l;              // lane l handles slot s this step
    if (s >= 0 && s < 20) {
      const int p  = s & 1;              // 0 -> unit A (2*tid), 1 -> unit B
      unsigned& rem = p ? remB : remA;
      const int ul = 2 * l + p;
      int beste = 0, bestc = 0, bestload = 999, bestidx = 0;
      for (int e = 0; e < C_REC; ++e) {
        if (!((rem >> e) & 1)) continue;
        int idx = sidx[ul * C_REC + e];
        for (int c = 0; c < NCOPY; ++c) {
          int ld = hist[s][(idx + 8 * c) & 31];
          if (ld < bestload) { bestload = ld; beste = e; bestc = c; bestidx = idx; }
        }
      }
      hist[s][(bestidx + 8 * bestc) & 31] = (unsigned char)(bestload + 1);
      rem &= ~(1u << beste);
      const int tid = w * 64 + l;
      offs[s * NT + tid] = bestc * 8192 + ((bestidx + 8 * bestc) & 2047) * 4;
      wtab[s * NT + tid] = sval[ul * C_REC + beste];
    }
    __syncthreads();
  }
}

// named-scalar hoist (R3 lesson: arrays -> scratch). Even slots feed unit A,
// odd slots unit B. Fallback = copy-0 direct offsets.
#define RDECL(k)                                                               \
  const int   oA##k = PERM ? offs[(2*(k)) * NT + tid]                          \
                           : ridx[u0 * C_REC + (k)] * 4;                       \
  const float wA##k = PERM ? wtab[(2*(k)) * NT + tid]                          \
                           : rvals[u0 * C_REC + (k)];                          \
  const int   oB##k = PERM ? offs[(2*(k)+1) * NT + tid]                        \
                           : ridx[(u0 + 1) * C_REC + (k)] * 4;                 \
  const float wB##k = PERM ? wtab[(2*(k)+1) * NT + tid]                        \
                           : rvals[(u0 + 1) * C_REC + (k)];

#define GAT(HC, k)                                                             \
  s0 += *(const float*)(smem + (HC) + oA##k) * wA##k;                          \
  s1 += *(const float*)(smem + (HC) + oB##k) * wB##k;

// One timestep. HC/HN = h cur/next (4 copies each), IR = input consumed
// (read + re-zero for reuse at t+2), IW = input built for t+1. xn holds
// x(t+1) entering the step; prefetch x(t+2) afterwards (vmcnt never drained
// by bar_lds -> latency hidden under the step).
#define STEP(HC, HN, IR, IW, DO_SCATTER, TSTEP)                                \
  {                                                                            \
    f32x2 in2 = *(f32x2*)(smem + (IR) + tid * 8);                              \
    *(f32x2*)(smem + (IR) + tid * 8) = (f32x2){0.f, 0.f};                      \
    float s0 = in2.x + bias2.x;                                                \
    float s1 = in2.y + bias2.y;                                                \
    GAT(HC, 0) GAT(HC, 1) GAT(HC, 2) GAT(HC, 3) GAT(HC, 4)                     \
    GAT(HC, 5) GAT(HC, 6) GAT(HC, 7) GAT(HC, 8) GAT(HC, 9)                     \
    if ((DO_SCATTER) && e0) atomicAdd((float*)(smem + (IW) + kcb), xn * kv);   \
    f32x2 hh = {fast_tanh(s0), fast_tanh(s1)};                                 \
    *(f32x2*)(smem + (HN) + pb0) = hh;                                         \
    *(f32x2*)(smem + (HN) + pb1) = hh;                                         \
    *(f32x2*)(smem + (HN) + pb2) = hh;                                         \
    *(f32x2*)(smem + (HN) + pb3) = hh;                                         \
    __builtin_nontemporal_store(hh, outp + (size_t)(TSTEP) * (UNITS / 2));     \
    if (e0) {                                                                  \
      int tnx = (TSTEP) + 2 < T ? (TSTEP) + 2 : T - 1;                         \
      xn = xin[tnx * D_IN + r0];                                               \
    }                                                                          \
    bar_lds();                                                                 \
  }

template <bool PERM>
__global__ __launch_bounds__(NT, 4) void reservoir_kernel(
    const float* __restrict__ inputs, const float* __restrict__ state0,
    const float* __restrict__ kvals,  const float* __restrict__ rvals,
    const float* __restrict__ bias,   const int* __restrict__ krows,
    const int* __restrict__ kcols,    const int* __restrict__ ridx,
    const int* __restrict__ offs,     const float* __restrict__ wtab,
    float* __restrict__ out)
{
  __shared__ __align__(16) char smem[LDS_BYTES];
  const int tid = threadIdx.x;
  const int b   = blockIdx.x;
  const int u0  = 2 * tid;

  // publish byte offsets for the thread's pair {u0,u0+1} into the 4 copies
  // (pair stays adjacent & b64-aligned: u0+8c is even, never wraps mid-pair)
  const int pb0 =         u0 * 4;
  const int pb1 = 8192  + ((u0 + 8)  & 2047) * 4;
  const int pb2 = 16384 + ((u0 + 16) & 2047) * 4;
  const int pb3 = 24576 + ((u0 + 24) & 2047) * 4;

  // zero input ping+pong; stage h(0) into all 4 copies of HA
  *(f32x2*)(smem + IA + tid * 8) = (f32x2){0.f, 0.f};
  *(f32x2*)(smem + IB + tid * 8) = (f32x2){0.f, 0.f};
  f32x2 h0 = *(const f32x2*)(state0 + b * UNITS + u0);
  *(f32x2*)(smem + HA + pb0) = h0;
  *(f32x2*)(smem + HA + pb1) = h0;
  *(f32x2*)(smem + HA + pb2) = h0;
  *(f32x2*)(smem + HA + pb3) = h0;

  RDECL(0) RDECL(1) RDECL(2) RDECL(3) RDECL(4)
  RDECL(5) RDECL(6) RDECL(7) RDECL(8) RDECL(9)

  const f32x2 bias2 = *(const f32x2*)(bias + u0);

  // input-kernel COO entry for this thread (960 entries)
  const bool e0 = tid < NNZ;
  const int   r0  = e0 ? krows[tid] : 0;
  const int   kcb = e0 ? kcols[tid] * 4 : 0;
  const float kv  = e0 ? kvals[tid] : 0.f;

  const float* xin  = inputs + (size_t)b * (T * D_IN);
  f32x2*       outp = (f32x2*)out + (size_t)b * (T * (UNITS / 2)) + tid;

  float xn = e0 ? xin[r0] : 0.f;    // x(0)
  __syncthreads();
  if (e0) atomicAdd((float*)(smem + IA + kcb), xn * kv);   // prime input(0)
  if (e0) xn = xin[D_IN + r0];      // x(1)
  bar_lds();

#pragma unroll 1
  for (int ts = 0; ts < T; ts += 2) {
    STEP(HA, HB, IA, IB, true,         ts);
    STEP(HB, HA, IB, IA, (ts + 2) < T, ts + 1);
  }
}

extern "C" void kernel_launch(void* const* d_in, const int* in_sizes, int n_in,
                              void* d_out, int out_size, void* d_ws, size_t ws_size,
                              hipStream_t stream) {
  const float* inputs = (const float*)d_in[0];
  const float* state0 = (const float*)d_in[1];
  const float* kvals  = (const float*)d_in[2];
  const float* rvals  = (const float*)d_in[3];
  const float* bias   = (const float*)d_in[4];
  const int*   krows  = (const int*)d_in[5];
  const int*   kcols  = (const int*)d_in[6];
  const int*   ridx   = (const int*)d_in[7];

  int*   offs = (int*)((char*)d_ws + OFFS_OFS);
  float* wtab = (float*)((char*)d_ws + WTAB_OFS);

  if (ws_size >= (size_t)WS_NEED) {
    prep_sched<<<dim3(16), dim3(64), 0, stream>>>(ridx, rvals, offs, wtab);
    reservoir_kernel<true><<<dim3(BATCH), dim3(NT), 0, stream>>>(
        inputs, state0, kvals, rvals, bias, krows, kcols, ridx, offs, wtab,
        (float*)d_out);
  } else {
    reservoir_kernel<false><<<dim3(BATCH), dim3(NT), 0, stream>>>(
        inputs, state0, kvals, rvals, bias, krows, kcols, ridx, offs, wtab,
        (float*)d_out);
  }
}

// Round 10
// 1203.247 us; speedup vs baseline: 4.3139x; 1.0418x over previous
//
#include <hip/hip_runtime.h>

namespace {
constexpr int UNITS = 2048;
constexpr int D_IN  = 96;
constexpr int BATCH = 64;
constexpr int T     = 512;
constexpr int NNZ   = 960;   // D_IN * C_IN
constexpr int C_REC = 10;
constexpr int NTH   = 512;   // threads/block; thread owns units 4t..4t+3

// LDS arena (bytes). h ping/pong each hold TWO copies: copy0 = unit u at
// dword u; copy1 = unit u at dword (u+8)&2047 (barrel shift by 8 dwords ->
// bank choice {b, b+8}). Gathers pick copy per (wave, slot) via prep.
constexpr int HA = 0;        // 2 x 8 KB
constexpr int HB = 16384;    // 2 x 8 KB
constexpr int IA = 32768;    // input_part ping (8 KB)
constexpr int IB = 40960;    // input_part pong (8 KB)
constexpr int LDS_BYTES = 49152;

// workspace: scheduled gather tables, [slot 0..39][tid] coalesced
constexpr int OFFS_OFS = 0;               // int  [40][512] final LDS byte offsets
constexpr int WTAB_OFS = 40 * NTH * 4;    // f32  [40][512]
constexpr int WS_NEED  = 80 * NTH * 4;    // 163840 B (proven available)
}

typedef float f32x4 __attribute__((ext_vector_type(4)));

// lgkm-only barrier: __syncthreads() drains vmcnt(0) -> would stall on the
// streaming out-stores and x prefetch loads every step.
__device__ __forceinline__ void bar_lds() {
  asm volatile("s_waitcnt lgkmcnt(0)\n\ts_barrier" ::: "memory");
}

__device__ __forceinline__ float fast_tanh(float x) {
  float e = __expf(2.0f * x);
  return 1.0f - __fdividef(2.0f, e + 1.0f);
}

// ---------------------------------------------------------------------------
// Prep: 8 blocks (one per main wave) x 64 lanes, slot-sequential with atomic
// feedback (R9's anti-diagonal greedy cost 189us wall — 103 barrier'd steps
// of dependent LDS reads; this is ~40 x ~3 rounds of lockstep atomics).
// Per slot: each lane proposes its r-th (remaining entry, copy) candidate,
// atomicAdd on the slot's bank histogram; accepted if prior load < 2
// (2-way is ~free per m136), else rollback and try next; round 5 forces.
// ---------------------------------------------------------------------------
__global__ __launch_bounds__(64) void prep_sched(
    const int* __restrict__ ridx, const float* __restrict__ rvals,
    int* __restrict__ offs, float* __restrict__ wtab)
{
  const int w = blockIdx.x, l = threadIdx.x;
  __shared__ int   sidx[256 * C_REC];   // this wave's 256 units
  __shared__ float sval[256 * C_REC];
  __shared__ int   hist[32];
  for (int i = l; i < 256 * C_REC; i += 64) {
    sidx[i] = ridx[w * 256 * C_REC + i];
    sval[i] = rvals[w * 256 * C_REC + i];
  }
  __syncthreads();
  const int tidm = w * 64 + l;          // main-kernel tid
  unsigned rem0 = 0x3FF, rem1 = 0x3FF, rem2 = 0x3FF, rem3 = 0x3FF;

#define SLOT(LU, K)                                                            \
  {                                                                            \
    if (l < 32) hist[l] = 0;                                                   \
    __syncthreads();                                                           \
    unsigned m = rem##LU;                                                      \
    const int nc = 2 * __popc(m);                                              \
    int pe = -1, pc = 0, pidx = 0;                                             \
    for (int r = 0; r < 6 && pe < 0; ++r) {                                    \
      const int rr = (r < nc) ? r : (r % nc);                                  \
      const int er = rr >> 1, cp = rr & 1;                                     \
      int cnt = 0, ce = 0;                                                     \
      _Pragma("unroll")                                                        \
      for (int e = 0; e < C_REC; ++e)                                          \
        if ((m >> e) & 1) { if (cnt == er) ce = e; ++cnt; }                    \
      const int idx  = sidx[(4 * l + LU) * C_REC + ce];                        \
      const int bank = (idx + 8 * cp) & 31;                                    \
      const int old  = atomicAdd(&hist[bank], 1);                              \
      if (old < 2 || r == 5) { pe = ce; pc = cp; pidx = idx; }                 \
      else atomicSub(&hist[bank], 1);                                          \
    }                                                                          \
    rem##LU = m & ~(1u << pe);                                                 \
    offs[((LU) * C_REC + (K)) * NTH + tidm] =                                  \
        pc * 8192 + ((pidx + 8 * pc) & 2047) * 4;                              \
    wtab[((LU) * C_REC + (K)) * NTH + tidm] = sval[(4 * l + LU) * C_REC + pe]; \
    __syncthreads();                                                           \
  }

#define SLOT10(LU)                                                             \
  SLOT(LU, 0) SLOT(LU, 1) SLOT(LU, 2) SLOT(LU, 3) SLOT(LU, 4)                  \
  SLOT(LU, 5) SLOT(LU, 6) SLOT(LU, 7) SLOT(LU, 8) SLOT(LU, 9)

  SLOT10(0) SLOT10(1) SLOT10(2) SLOT10(3)
#undef SLOT10
#undef SLOT
}

// named-scalar hoist (R3 lesson: arrays -> scratch)
#define RDECL(LU, K)                                                           \
  const int   o##LU##_##K = PERM ? offs[((LU) * C_REC + (K)) * NTH + tid]      \
                                 : ridx[(u0 + (LU)) * C_REC + (K)] * 4;        \
  const float w##LU##_##K = PERM ? wtab[((LU) * C_REC + (K)) * NTH + tid]      \
                                 : rvals[(u0 + (LU)) * C_REC + (K)];
#define RDECL10(LU)                                                            \
  RDECL(LU, 0) RDECL(LU, 1) RDECL(LU, 2) RDECL(LU, 3) RDECL(LU, 4)             \
  RDECL(LU, 5) RDECL(LU, 6) RDECL(LU, 7) RDECL(LU, 8) RDECL(LU, 9)

#define GAT(HC, LU, K)                                                         \
  s##LU += *(const float*)(smem + (HC) + o##LU##_##K) * w##LU##_##K;
#define GAT10(HC, LU)                                                          \
  GAT(HC, LU, 0) GAT(HC, LU, 1) GAT(HC, LU, 2) GAT(HC, LU, 3) GAT(HC, LU, 4)   \
  GAT(HC, LU, 5) GAT(HC, LU, 6) GAT(HC, LU, 7) GAT(HC, LU, 8) GAT(HC, LU, 9)

// One timestep, 4 units/thread. HC/HN = h cur/next (2 copies each), IR =
// input consumed (b128 read + re-zero), IW = input built for t+1. x1/x2 hold
// x(t+1) entering the step; prefetch x(t+2) afterwards (bar_lds never drains
// vmcnt -> prefetch latency hidden under the step).
#define STEP(HC, HN, IR, IW, DO_SCATTER, TSTEP)                                \
  {                                                                            \
    f32x4 in4 = *(f32x4*)(smem + (IR) + tid * 16);                             \
    *(f32x4*)(smem + (IR) + tid * 16) = (f32x4){0.f, 0.f, 0.f, 0.f};           \
    float s0 = in4.x + bias4.x, s1 = in4.y + bias4.y;                          \
    float s2 = in4.z + bias4.z, s3 = in4.w + bias4.w;                          \
    GAT10(HC, 0) GAT10(HC, 1) GAT10(HC, 2) GAT10(HC, 3)                        \
    if (DO_SCATTER) {                                                          \
      atomicAdd((float*)(smem + (IW) + c1), x1 * v1);                          \
      if (e2) atomicAdd((float*)(smem + (IW) + c2), x2 * v2);                  \
    }                                                                          \
    f32x4 hh = {fast_tanh(s0), fast_tanh(s1), fast_tanh(s2), fast_tanh(s3)};   \
    *(f32x4*)(smem + (HN) + pb0) = hh;                                         \
    *(f32x4*)(smem + (HN) + pb1) = hh;                                         \
    __builtin_nontemporal_store(hh, outp + (size_t)(TSTEP) * (UNITS / 4));     \
    {                                                                          \
      int tnx = (TSTEP) + 2 < T ? (TSTEP) + 2 : T - 1;                         \
      x1 = xin[tnx * D_IN + r1];                                               \
      if (e2) x2 = xin[tnx * D_IN + r2];                                       \
    }                                                                          \
    bar_lds();                                                                 \
  }

template <bool PERM>
__global__ __launch_bounds__(NTH, 2) void reservoir_kernel(
    const float* __restrict__ inputs, const float* __restrict__ state0,
    const float* __restrict__ kvals,  const float* __restrict__ rvals,
    const float* __restrict__ bias,   const int* __restrict__ krows,
    const int* __restrict__ kcols,    const int* __restrict__ ridx,
    const int* __restrict__ offs,     const float* __restrict__ wtab,
    float* __restrict__ out)
{
  __shared__ __align__(16) char smem[LDS_BYTES];
  const int tid = threadIdx.x;
  const int b   = blockIdx.x;
  const int u0  = 4 * tid;

  // publish byte offsets for units u0..u0+3 in the two copies (both b128-
  // aligned; (u0+8)&2047 is a multiple of 4, wrap happens between threads)
  const int pb0 = u0 * 4;
  const int pb1 = 8192 + ((u0 + 8) & 2047) * 4;

  // zero input ping+pong; stage h(0) into both copies of HA
  *(f32x4*)(smem + IA + tid * 16) = (f32x4){0.f, 0.f, 0.f, 0.f};
  *(f32x4*)(smem + IB + tid * 16) = (f32x4){0.f, 0.f, 0.f, 0.f};
  f32x4 h0 = *(const f32x4*)(state0 + b * UNITS + u0);
  *(f32x4*)(smem + HA + pb0) = h0;
  *(f32x4*)(smem + HA + pb1) = h0;

  RDECL10(0) RDECL10(1) RDECL10(2) RDECL10(3)

  const f32x4 bias4 = *(const f32x4*)(bias + u0);

  // input-kernel COO entries tid and tid+512 (960 total)
  const bool e2 = tid < NNZ - NTH;
  const int   r1 = krows[tid];
  const int   c1 = kcols[tid] * 4;
  const float v1 = kvals[tid];
  const int   r2 = e2 ? krows[NTH + tid] : 0;
  const int   c2 = e2 ? kcols[NTH + tid] * 4 : 0;
  const float v2 = e2 ? kvals[NTH + tid] : 0.f;

  const float* xin  = inputs + (size_t)b * (T * D_IN);
  f32x4*       outp = (f32x4*)out + (size_t)b * (T * (UNITS / 4)) + tid;

  float x1 = xin[r1];               // x(0)
  float x2 = e2 ? xin[r2] : 0.f;
  __syncthreads();
  atomicAdd((float*)(smem + IA + c1), x1 * v1);   // prime input(0)
  if (e2) atomicAdd((float*)(smem + IA + c2), x2 * v2);
  x1 = xin[D_IN + r1];              // x(1)
  if (e2) x2 = xin[D_IN + r2];
  bar_lds();

#pragma unroll 1
  for (int ts = 0; ts < T; ts += 2) {
    STEP(HA, HB, IA, IB, true,         ts);
    STEP(HB, HA, IB, IA, (ts + 2) < T, ts + 1);
  }
}

extern "C" void kernel_launch(void* const* d_in, const int* in_sizes, int n_in,
                              void* d_out, int out_size, void* d_ws, size_t ws_size,
                              hipStream_t stream) {
  const float* inputs = (const float*)d_in[0];
  const float* state0 = (const float*)d_in[1];
  const float* kvals  = (const float*)d_in[2];
  const float* rvals  = (const float*)d_in[3];
  const float* bias   = (const float*)d_in[4];
  const int*   krows  = (const int*)d_in[5];
  const int*   kcols  = (const int*)d_in[6];
  const int*   ridx   = (const int*)d_in[7];

  int*   offs = (int*)((char*)d_ws + OFFS_OFS);
  float* wtab = (float*)((char*)d_ws + WTAB_OFS);

  if (ws_size >= (size_t)WS_NEED) {
    prep_sched<<<dim3(8), dim3(64), 0, stream>>>(ridx, rvals, offs, wtab);
    reservoir_kernel<true><<<dim3(BATCH), dim3(NTH), 0, stream>>>(
        inputs, state0, kvals, rvals, bias, krows, kcols, ridx, offs, wtab,
        (float*)d_out);
  } else {
    reservoir_kernel<false><<<dim3(BATCH), dim3(NTH), 0, stream>>>(
        inputs, state0, kvals, rvals, bias, krows, kcols, ridx, offs, wtab,
        (float*)d_out);
  }
}

// Round 11
// 1147.943 us; speedup vs baseline: 4.5217x; 1.0482x over previous
//
#include <hip/hip_runtime.h>

namespace {
constexpr int UNITS = 2048;
constexpr int D_IN  = 96;
constexpr int BATCH = 64;
constexpr int T     = 512;
constexpr int NNZ   = 960;   // D_IN * C_IN
constexpr int C_REC = 10;
constexpr int NT    = 1024;  // threads/block; thread owns units 2t, 2t+1

// LDS arena (bytes). h ping/pong each hold TWO copies:
//   copy0: unit u at dword u                       (bank = u & 31)
//   copy1: pair p=u>>1 at pair-slot sig(p)=p^((p>>4)&15), unit at
//          dword 2*sig(p)+(u&1)                    (bank decorrelated by
//          bits 4-7 of p -> a copy0 collision class spreads across banks)
// R9/R10 ERROR: barrel-shift copies (+8c) shift colliding lanes EQUALLY ->
// zero freedom. XOR-folding the pair index actually decorrelates.
constexpr int HA = 0;        // 2 x 8 KB
constexpr int HB = 16384;    // 2 x 8 KB
constexpr int IA = 32768;    // input_part ping (8 KB)
constexpr int IB = 40960;    // input_part pong (8 KB)
constexpr int LDS_BYTES = 49152;

// workspace: scheduled gather tables, [slot 0..19][tid] coalesced
constexpr int OFFS_OFS = 0;              // int  [20][1024] final LDS byte offsets
constexpr int WTAB_OFS = 20 * NT * 4;    // f32  [20][1024]
constexpr int WS_NEED  = 40 * NT * 4;    // 163840 B (proven available)
}

typedef float f32x2 __attribute__((ext_vector_type(2)));
typedef float f32x4 __attribute__((ext_vector_type(4)));

// lgkm-only barrier: __syncthreads() drains vmcnt(0) -> would stall on the
// streaming out-stores and x prefetch loads every step.
__device__ __forceinline__ void bar_lds() {
  asm volatile("s_waitcnt lgkmcnt(0)\n\ts_barrier" ::: "memory");
}

__device__ __forceinline__ float fast_tanh(float x) {
  float e = __expf(2.0f * x);
  return 1.0f - __fdividef(2.0f, e + 1.0f);
}

// copy1 byte offset for gathering unit idx
__device__ __forceinline__ int c1_byte(int idx) {
  int p = idx >> 1;
  return 8192 + (2 * (p ^ ((p >> 4) & 15)) + (idx & 1)) * 4;
}

// ---------------------------------------------------------------------------
// Prep: 16 blocks (one per main wave) x 64 lanes; slot-sequential greedy with
// atomic feedback (fast: ~20 barrier'd rounds, no anti-diagonal). Per slot,
// each lane proposes its r-th (remaining entry, copy) candidate, atomicAdd on
// the slot's 32-bank histogram, accept if prior load < 2 (2/bank is free per
// m136), rollback+retry otherwise; round 5 forces.
// ---------------------------------------------------------------------------
__global__ __launch_bounds__(64) void prep_sched(
    const int* __restrict__ ridx, const float* __restrict__ rvals,
    int* __restrict__ offs, float* __restrict__ wtab)
{
  const int w = blockIdx.x, l = threadIdx.x;
  __shared__ int   sidx[128 * C_REC];   // this wave's 128 units
  __shared__ float sval[128 * C_REC];
  __shared__ int   hist[32];
  for (int i = l; i < 128 * C_REC; i += 64) {
    sidx[i] = ridx[w * 128 * C_REC + i];
    sval[i] = rvals[w * 128 * C_REC + i];
  }
  __syncthreads();
  const int tidm = w * 64 + l;          // main-kernel tid
  unsigned rem0 = 0x3FF, rem1 = 0x3FF;

  for (int s = 0; s < 20; ++s) {
    if (l < 32) hist[l] = 0;
    __syncthreads();
    const int p = s & 1;                // even slot -> unit A, odd -> unit B
    unsigned& rem = p ? rem1 : rem0;
    const int ul = 2 * l + p;
    const unsigned m = rem;
    const int nc = 2 * __popc(m);
    int pe = -1, pidx = 0, pcp = 0;
    for (int r = 0; r < 6 && pe < 0; ++r) {
      const int rr = (r < nc) ? r : (r % nc);
      const int er = rr >> 1, cp = rr & 1;
      int cnt = 0, ce = 0;
#pragma unroll
      for (int e = 0; e < C_REC; ++e)
        if ((m >> e) & 1) { if (cnt == er) ce = e; ++cnt; }
      const int idx  = sidx[ul * C_REC + ce];
      const int bank = cp ? ((c1_byte(idx) >> 2) & 31) : (idx & 31);
      const int old  = atomicAdd(&hist[bank], 1);
      if (old < 2 || r == 5) { pe = ce; pcp = cp; pidx = idx; }
      else atomicSub(&hist[bank], 1);
    }
    rem = m & ~(1u << pe);
    offs[s * NT + tidm] = pcp ? c1_byte(pidx) : pidx * 4;
    wtab[s * NT + tidm] = sval[ul * C_REC + pe];
    __syncthreads();
  }
}

// named-scalar hoist (R3 lesson: arrays -> scratch). Even slots feed unit A,
// odd slots unit B. Fallback = copy-0 direct offsets.
#define RDECL(k)                                                               \
  const int   oA##k = PERM ? offs[(2*(k)) * NT + tid]                          \
                           : ridx[u0 * C_REC + (k)] * 4;                       \
  const float wA##k = PERM ? wtab[(2*(k)) * NT + tid]                          \
                           : rvals[u0 * C_REC + (k)];                          \
  const int   oB##k = PERM ? offs[(2*(k)+1) * NT + tid]                        \
                           : ridx[(u0 + 1) * C_REC + (k)] * 4;                 \
  const float wB##k = PERM ? wtab[(2*(k)+1) * NT + tid]                        \
                           : rvals[(u0 + 1) * C_REC + (k)];

#define GAT(HC, k)                                                             \
  s0 += *(const float*)(smem + (HC) + oA##k) * wA##k;                          \
  s1 += *(const float*)(smem + (HC) + oB##k) * wB##k;

// One timestep. HC/HN = h cur/next (2 copies each), IR = input consumed
// (read + re-zero for reuse at t+2), IW = input built for t+1. xn holds
// x(t+1) entering the step; prefetch x(t+2) afterwards (bar_lds never drains
// vmcnt -> prefetch latency hidden under the step).
#define STEP(HC, HN, IR, IW, DO_SCATTER, TSTEP)                                \
  {                                                                            \
    f32x2 in2 = *(f32x2*)(smem + (IR) + tid * 8);                              \
    *(f32x2*)(smem + (IR) + tid * 8) = (f32x2){0.f, 0.f};                      \
    float s0 = in2.x + bias2.x;                                                \
    float s1 = in2.y + bias2.y;                                                \
    GAT(HC, 0) GAT(HC, 1) GAT(HC, 2) GAT(HC, 3) GAT(HC, 4)                     \
    GAT(HC, 5) GAT(HC, 6) GAT(HC, 7) GAT(HC, 8) GAT(HC, 9)                     \
    if ((DO_SCATTER) && e0) atomicAdd((float*)(smem + (IW) + kcb), xn * kv);   \
    f32x2 hh = {fast_tanh(s0), fast_tanh(s1)};                                 \
    *(f32x2*)(smem + (HN) + pb0) = hh;                                         \
    *(f32x2*)(smem + (HN) + pb1) = hh;                                         \
    __builtin_nontemporal_store(hh, outp + (size_t)(TSTEP) * (UNITS / 2));     \
    if (e0) {                                                                  \
      int tnx = (TSTEP) + 2 < T ? (TSTEP) + 2 : T - 1;                         \
      xn = xin[tnx * D_IN + r0];                                               \
    }                                                                          \
    bar_lds();                                                                 \
  }

template <bool PERM>
__global__ __launch_bounds__(NT, 4) void reservoir_kernel(
    const float* __restrict__ inputs, const float* __restrict__ state0,
    const float* __restrict__ kvals,  const float* __restrict__ rvals,
    const float* __restrict__ bias,   const int* __restrict__ krows,
    const int* __restrict__ kcols,    const int* __restrict__ ridx,
    const int* __restrict__ offs,     const float* __restrict__ wtab,
    float* __restrict__ out)
{
  __shared__ __align__(16) char smem[LDS_BYTES];
  const int tid = threadIdx.x;
  const int b   = blockIdx.x;
  const int u0  = 2 * tid;

  // publish byte offsets for the pair {u0,u0+1}: copy0 at dword u0, copy1 at
  // pair-slot sig(tid) (both b64-aligned)
  const int pb0 = u0 * 4;
  const int pb1 = 8192 + (tid ^ ((tid >> 4) & 15)) * 8;

  // zero input ping+pong; stage h(0) into both copies of HA
  *(f32x2*)(smem + IA + tid * 8) = (f32x2){0.f, 0.f};
  *(f32x2*)(smem + IB + tid * 8) = (f32x2){0.f, 0.f};
  f32x2 h0 = *(const f32x2*)(state0 + b * UNITS + u0);
  *(f32x2*)(smem + HA + pb0) = h0;
  *(f32x2*)(smem + HA + pb1) = h0;

  RDECL(0) RDECL(1) RDECL(2) RDECL(3) RDECL(4)
  RDECL(5) RDECL(6) RDECL(7) RDECL(8) RDECL(9)

  const f32x2 bias2 = *(const f32x2*)(bias + u0);

  // input-kernel COO entry for this thread (960 entries)
  const bool e0 = tid < NNZ;
  const int   r0  = e0 ? krows[tid] : 0;
  const int   kcb = e0 ? kcols[tid] * 4 : 0;
  const float kv  = e0 ? kvals[tid] : 0.f;

  const float* xin  = inputs + (size_t)b * (T * D_IN);
  f32x2*       outp = (f32x2*)out + (size_t)b * (T * (UNITS / 2)) + tid;

  float xn = e0 ? xin[r0] : 0.f;    // x(0)
  __syncthreads();
  if (e0) atomicAdd((float*)(smem + IA + kcb), xn * kv);   // prime input(0)
  if (e0) xn = xin[D_IN + r0];      // x(1)
  bar_lds();

#pragma unroll 1
  for (int ts = 0; ts < T; ts += 2) {
    STEP(HA, HB, IA, IB, true,         ts);
    STEP(HB, HA, IB, IA, (ts + 2) < T, ts + 1);
  }
}

extern "C" void kernel_launch(void* const* d_in, const int* in_sizes, int n_in,
                              void* d_out, int out_size, void* d_ws, size_t ws_size,
                              hipStream_t stream) {
  const float* inputs = (const float*)d_in[0];
  const float* state0 = (const float*)d_in[1];
  const float* kvals  = (const float*)d_in[2];
  const float* rvals  = (const float*)d_in[3];
  const float* bias   = (const float*)d_in[4];
  const int*   krows  = (const int*)d_in[5];
  const int*   kcols  = (const int*)d_in[6];
  const int*   ridx   = (const int*)d_in[7];

  int*   offs = (int*)((char*)d_ws + OFFS_OFS);
  float* wtab = (float*)((char*)d_ws + WTAB_OFS);

  if (ws_size >= (size_t)WS_NEED) {
    prep_sched<<<dim3(16), dim3(64), 0, stream>>>(ridx, rvals, offs, wtab);
    reservoir_kernel<true><<<dim3(BATCH), dim3(NT), 0, stream>>>(
        inputs, state0, kvals, rvals, bias, krows, kcols, ridx, offs, wtab,
        (float*)d_out);
  } else {
    reservoir_kernel<false><<<dim3(BATCH), dim3(NT), 0, stream>>>(
        inputs, state0, kvals, rvals, bias, krows, kcols, ridx, offs, wtab,
        (float*)d_out);
  }
}

// Round 12
// 1069.655 us; speedup vs baseline: 4.8527x; 1.0732x over previous
//
#include <hip/hip_runtime.h>

namespace {
constexpr int UNITS = 2048;
constexpr int D_IN  = 96;
constexpr int BATCH = 64;
constexpr int T     = 512;
constexpr int NNZ   = 960;   // D_IN * C_IN
constexpr int C_REC = 10;
constexpr int NT    = 1024;  // threads/block; thread owns units 2t, 2t+1

// LDS arena (bytes). h ping/pong each hold TWO copies:
//   copy0: unit u at dword u
//   copy1: pair p=u>>1 at pair-slot p^((p>>4)&15)  (bank decorrelated)
constexpr int HA = 0;        // 2 x 8 KB
constexpr int HB = 16384;    // 2 x 8 KB
constexpr int IA = 32768;    // input_part ping (8 KB)
constexpr int IB = 40960;    // input_part pong (8 KB)
constexpr int LDS_BYTES = 49152;

// workspace (bytes): compressed so gather + scatter tables fit well under
// the proven-available 160 KB
constexpr int OFFS_OFS = 0;                        // u16 [20][1024] gather byte-offs
constexpr int WTAB_OFS = 20 * NT * 2;              // f32 [20][1024] @ 40960
constexpr int SCOL_OFS = WTAB_OFS + 20 * NT * 4;   // u16 [960] col byte-off @ 122880
constexpr int SROW_OFS = SCOL_OFS + NNZ * 2;       // u16 [960] row
constexpr int SVAL_OFS = SROW_OFS + NNZ * 2;       // f32 [960] val @ 126720
constexpr int WS_NEED  = SVAL_OFS + NNZ * 4;       // 130560 B
}

typedef float f32x2 __attribute__((ext_vector_type(2)));

// lgkm-only barrier: __syncthreads() drains vmcnt(0) -> would stall on the
// streaming out-stores and x prefetch loads every step.
__device__ __forceinline__ void bar_lds() {
  asm volatile("s_waitcnt lgkmcnt(0)\n\ts_barrier" ::: "memory");
}

__device__ __forceinline__ float fast_tanh(float x) {
  float e = __expf(2.0f * x);
  return 1.0f - __fdividef(2.0f, e + 1.0f);
}

// copy1 byte offset for unit idx (matches main kernel's publish pb1)
__device__ __forceinline__ int c1_byte(int idx) {
  int p = idx >> 1;
  return 8192 + (2 * (p ^ ((p >> 4) & 15)) + (idx & 1)) * 4;
}

// ---------------------------------------------------------------------------
// Prep, 17 blocks x 64 threads.
// Blocks 0..15: gather scheduling for main wave w. KEY FIX vs R10/R11: LDS
// resolves a wave64 op as TWO 32-lane halves -> histogram must be per
// (half, bank) [64 bins] and the target is <=1 lane/bank/half (a bank
// permutation), not <=2 over 64 lanes. Threshold schedule: rounds 0-2 accept
// only empty bank (perfect matching), 3-6 accept <=2, round 7 forces.
// Lane-hashed candidate rotation decorrelates lockstep proposals.
// Block 16: scatter assignment — counting-sort the 960 COO entries by column
// bank, deal round-robin over the 30 (wave,half) scatter slots -> ~1 per
// bank per half for the input-scatter atomics as well.
// ---------------------------------------------------------------------------
__global__ __launch_bounds__(64) void prep_sched(
    const int* __restrict__ ridx, const float* __restrict__ rvals,
    const int* __restrict__ krows, const int* __restrict__ kcols,
    const float* __restrict__ kvals,
    unsigned short* __restrict__ offs16, float* __restrict__ wtab,
    unsigned short* __restrict__ scol, unsigned short* __restrict__ srow,
    float* __restrict__ sval)
{
  const int l = threadIdx.x;
  if (blockIdx.x < 16) {
    const int w = blockIdx.x;
    __shared__ int   sidx[128 * C_REC];
    __shared__ float svalw[128 * C_REC];
    __shared__ int   hist[64];              // [half][bank]
    for (int i = l; i < 128 * C_REC; i += 64) {
      sidx[i]  = ridx[w * 128 * C_REC + i];
      svalw[i] = rvals[w * 128 * C_REC + i];
    }
    __syncthreads();
    const int tidm  = w * 64 + l;
    const int hbase = (l >> 5) << 5;        // 0 for lanes 0-31, 32 for 32-63
    const unsigned lh = ((unsigned)l * 2654435761u) >> 27;  // lane hash 0..31
    unsigned rem0 = 0x3FF, rem1 = 0x3FF;
    for (int s = 0; s < 20; ++s) {
      hist[l] = 0;
      __syncthreads();
      const int p = s & 1;                  // even slot -> unit A, odd -> B
      unsigned& rem = p ? rem1 : rem0;
      const int ul = 2 * l + p;
      const unsigned m = rem;
      const int nc = 2 * __popc(m);
      int pe = -1, pidx = 0, pcp = 0;
      for (int r = 0; r < 8 && pe < 0; ++r) {
        const int thr = (r < 3) ? 1 : 2;
        const int rr  = (int)((r + lh) % (unsigned)nc);
        const int er = rr >> 1, cp = rr & 1;
        int cnt = 0, ce = 0;
#pragma unroll
        for (int e = 0; e < C_REC; ++e)
          if ((m >> e) & 1) { if (cnt == er) ce = e; ++cnt; }
        const int idx  = sidx[ul * C_REC + ce];
        const int byte = cp ? c1_byte(idx) : idx * 4;
        const int bank = (byte >> 2) & 31;
        const int old  = atomicAdd(&hist[hbase + bank], 1);
        if (old < thr || r == 7) { pe = ce; pcp = cp; pidx = idx; }
        else atomicSub(&hist[hbase + bank], 1);
      }
      rem = m & ~(1u << pe);
      offs16[s * NT + tidm] =
          (unsigned short)(pcp ? c1_byte(pidx) : pidx * 4);
      wtab[s * NT + tidm] = svalw[ul * C_REC + pe];
      __syncthreads();
    }
  } else {
    // scatter assignment (deterministic counting sort by bank)
    __shared__ int lc[64][32];
    __shared__ int base[64][32];
    __shared__ int tot[32];
    __shared__ int bankstart[32];
    for (int b2 = 0; b2 < 32; ++b2) lc[l][b2] = 0;
    __syncthreads();
    for (int k = 0; k < NNZ / 64; ++k)
      ++lc[l][kcols[l * (NNZ / 64) + k] & 31];
    __syncthreads();
    if (l < 32) {                           // prefix over threads, bank l
      int run = 0;
      for (int t = 0; t < 64; ++t) { base[t][l] = run; run += lc[t][l]; }
      tot[l] = run;
    }
    __syncthreads();
    if (l == 0) {
      int run = 0;
      for (int b2 = 0; b2 < 32; ++b2) { bankstart[b2] = run; run += tot[b2]; }
    }
    for (int b2 = 0; b2 < 32; ++b2) lc[l][b2] = 0;   // reuse as running pos
    __syncthreads();
    for (int k = 0; k < NNZ / 64; ++k) {
      const int i  = l * (NNZ / 64) + k;
      const int b2 = kcols[i] & 31;
      const int rank = bankstart[b2] + base[l][b2] + lc[l][b2]++;
      const int slot = rank % 30;           // (wave 0..14, half)
      const int li   = rank / 30;           // lane-in-half 0..31
      const int tid  = (slot >> 1) * 64 + (slot & 1) * 32 + li;  // 0..959
      scol[tid] = (unsigned short)(kcols[i] * 4);
      srow[tid] = (unsigned short)krows[i];
      sval[tid] = kvals[i];
    }
  }
}

// named-scalar hoist (R3 lesson: arrays -> scratch). Even slots feed unit A,
// odd slots unit B. Fallback = copy-0 direct offsets.
#define RDECL(k)                                                               \
  const int   oA##k = PERM ? (int)offs16[(2*(k)) * NT + tid]                   \
                           : ridx[u0 * C_REC + (k)] * 4;                       \
  const float wA##k = PERM ? wtab[(2*(k)) * NT + tid]                          \
                           : rvals[u0 * C_REC + (k)];                          \
  const int   oB##k = PERM ? (int)offs16[(2*(k)+1) * NT + tid]                 \
                           : ridx[(u0 + 1) * C_REC + (k)] * 4;                 \
  const float wB##k = PERM ? wtab[(2*(k)+1) * NT + tid]                        \
                           : rvals[(u0 + 1) * C_REC + (k)];

#define GAT(HC, k)                                                             \
  s0 += *(const float*)(smem + (HC) + oA##k) * wA##k;                          \
  s1 += *(const float*)(smem + (HC) + oB##k) * wB##k;

// One timestep. HC/HN = h cur/next (2 copies each), IR = input consumed
// (read + re-zero for reuse at t+2), IW = input built for t+1. xn holds
// x(t+1) entering the step; prefetch x(t+2) afterwards (bar_lds never drains
// vmcnt -> prefetch latency hidden under the step).
#define STEP(HC, HN, IR, IW, DO_SCATTER, TSTEP)                                \
  {                                                                            \
    f32x2 in2 = *(f32x2*)(smem + (IR) + tid * 8);                              \
    *(f32x2*)(smem + (IR) + tid * 8) = (f32x2){0.f, 0.f};                      \
    float s0 = in2.x + bias2.x;                                                \
    float s1 = in2.y + bias2.y;                                                \
    GAT(HC, 0) GAT(HC, 1) GAT(HC, 2) GAT(HC, 3) GAT(HC, 4)                     \
    GAT(HC, 5) GAT(HC, 6) GAT(HC, 7) GAT(HC, 8) GAT(HC, 9)                     \
    if ((DO_SCATTER) && e0) atomicAdd((float*)(smem + (IW) + kcb), xn * kv);   \
    f32x2 hh = {fast_tanh(s0), fast_tanh(s1)};                                 \
    *(f32x2*)(smem + (HN) + pb0) = hh;                                         \
    *(f32x2*)(smem + (HN) + pb1) = hh;                                         \
    __builtin_nontemporal_store(hh, outp + (size_t)(TSTEP) * (UNITS / 2));     \
    if (e0) {                                                                  \
      int tnx = (TSTEP) + 2 < T ? (TSTEP) + 2 : T - 1;                         \
      xn = xin[tnx * D_IN + r0];                                               \
    }                                                                          \
    bar_lds();                                                                 \
  }

template <bool PERM>
__global__ __launch_bounds__(NT, 4) void reservoir_kernel(
    const float* __restrict__ inputs, const float* __restrict__ state0,
    const float* __restrict__ kvals,  const float* __restrict__ rvals,
    const float* __restrict__ bias,   const int* __restrict__ krows,
    const int* __restrict__ kcols,    const int* __restrict__ ridx,
    const unsigned short* __restrict__ offs16, const float* __restrict__ wtab,
    const unsigned short* __restrict__ scol,
    const unsigned short* __restrict__ srow, const float* __restrict__ sval,
    float* __restrict__ out)
{
  __shared__ __align__(16) char smem[LDS_BYTES];
  const int tid = threadIdx.x;
  const int b   = blockIdx.x;
  const int u0  = 2 * tid;

  // publish byte offsets for the pair {u0,u0+1}: copy0 at dword u0, copy1 at
  // pair-slot tid^((tid>>4)&15) (both b64-aligned)
  const int pb0 = u0 * 4;
  const int pb1 = 8192 + (tid ^ ((tid >> 4) & 15)) * 8;

  // zero input ping+pong; stage h(0) into both copies of HA
  *(f32x2*)(smem + IA + tid * 8) = (f32x2){0.f, 0.f};
  *(f32x2*)(smem + IB + tid * 8) = (f32x2){0.f, 0.f};
  f32x2 h0 = *(const f32x2*)(state0 + b * UNITS + u0);
  *(f32x2*)(smem + HA + pb0) = h0;
  *(f32x2*)(smem + HA + pb1) = h0;

  RDECL(0) RDECL(1) RDECL(2) RDECL(3) RDECL(4)
  RDECL(5) RDECL(6) RDECL(7) RDECL(8) RDECL(9)

  const f32x2 bias2 = *(const f32x2*)(bias + u0);

  // input-kernel COO entry: bank-scheduled assignment (PERM) or raw COO
  const bool e0 = tid < NNZ;
  int r0 = 0, kcb = 0; float kv = 0.f;
  if (PERM) {
    if (e0) { r0 = srow[tid]; kcb = scol[tid]; kv = sval[tid]; }
  } else {
    if (e0) { r0 = krows[tid]; kcb = kcols[tid] * 4; kv = kvals[tid]; }
  }

  const float* xin  = inputs + (size_t)b * (T * D_IN);
  f32x2*       outp = (f32x2*)out + (size_t)b * (T * (UNITS / 2)) + tid;

  float xn = e0 ? xin[r0] : 0.f;    // x(0)
  __syncthreads();
  if (e0) atomicAdd((float*)(smem + IA + kcb), xn * kv);   // prime input(0)
  if (e0) xn = xin[D_IN + r0];      // x(1)
  bar_lds();

#pragma unroll 1
  for (int ts = 0; ts < T; ts += 2) {
    STEP(HA, HB, IA, IB, true,         ts);
    STEP(HB, HA, IB, IA, (ts + 2) < T, ts + 1);
  }
}

extern "C" void kernel_launch(void* const* d_in, const int* in_sizes, int n_in,
                              void* d_out, int out_size, void* d_ws, size_t ws_size,
                              hipStream_t stream) {
  const float* inputs = (const float*)d_in[0];
  const float* state0 = (const float*)d_in[1];
  const float* kvals  = (const float*)d_in[2];
  const float* rvals  = (const float*)d_in[3];
  const float* bias   = (const float*)d_in[4];
  const int*   krows  = (const int*)d_in[5];
  const int*   kcols  = (const int*)d_in[6];
  const int*   ridx   = (const int*)d_in[7];

  unsigned short* offs16 = (unsigned short*)((char*)d_ws + OFFS_OFS);
  float*          wtab   = (float*)((char*)d_ws + WTAB_OFS);
  unsigned short* scol   = (unsigned short*)((char*)d_ws + SCOL_OFS);
  unsigned short* srow   = (unsigned short*)((char*)d_ws + SROW_OFS);
  float*          sval   = (float*)((char*)d_ws + SVAL_OFS);

  if (ws_size >= (size_t)WS_NEED) {
    prep_sched<<<dim3(17), dim3(64), 0, stream>>>(
        ridx, rvals, krows, kcols, kvals, offs16, wtab, scol, srow, sval);
    reservoir_kernel<true><<<dim3(BATCH), dim3(NT), 0, stream>>>(
        inputs, state0, kvals, rvals, bias, krows, kcols, ridx,
        offs16, wtab, scol, srow, sval, (float*)d_out);
  } else {
    reservoir_kernel<false><<<dim3(BATCH), dim3(NT), 0, stream>>>(
        inputs, state0, kvals, rvals, bias, krows, kcols, ridx,
        offs16, wtab, scol, srow, sval, (float*)d_out);
  }
}